// Round 1
// baseline (1202.353 us; speedup 1.0000x reference)
//
#include <hip/hip_runtime.h>
#include <cstdint>
#include <cstddef>

static constexpr int IN_DIM = 512;
static constexpr int HID = 128;
static constexpr int OUT_DIM = 64;

// ---------------- CSR construction (counting sort by dst, rebuilt every call) ----------------

__global__ void k_hist(const int* __restrict__ dst, int E, int* __restrict__ counts) {
    int e = blockIdx.x * blockDim.x + threadIdx.x;
    if (e < E) atomicAdd(&counts[dst[e]], 1);
}

__global__ void k_scan1(const int* __restrict__ counts, int N, int* __restrict__ offs,
                        int* __restrict__ bsums) {
    __shared__ int sm[1024];
    int i = blockIdx.x * 1024 + threadIdx.x;
    int v = (i < N) ? counts[i] : 0;
    sm[threadIdx.x] = v;
    __syncthreads();
    for (int d = 1; d < 1024; d <<= 1) {
        int t = (threadIdx.x >= d) ? sm[threadIdx.x - d] : 0;
        __syncthreads();
        sm[threadIdx.x] += t;
        __syncthreads();
    }
    if (i < N) offs[i] = sm[threadIdx.x] - v;        // exclusive within block
    if (threadIdx.x == 1023) bsums[blockIdx.x] = sm[1023];
}

__global__ void k_scan2(int* __restrict__ bsums, int nb) {
    __shared__ int sm[256];
    int x = threadIdx.x;
    int v = (x < nb) ? bsums[x] : 0;
    sm[x] = v;
    __syncthreads();
    for (int d = 1; d < 256; d <<= 1) {
        int t = (x >= d) ? sm[x - d] : 0;
        __syncthreads();
        sm[x] += t;
        __syncthreads();
    }
    if (x < nb) bsums[x] = sm[x] - v;                // exclusive block offsets
}

__global__ void k_scan3(int* __restrict__ offs, const int* __restrict__ bsums, int N, int E,
                        int* __restrict__ cursor) {
    int i = blockIdx.x * 1024 + threadIdx.x;
    if (i < N) {
        int o = offs[i] + bsums[blockIdx.x];
        offs[i] = o;
        cursor[i] = o;
    }
    if (blockIdx.x == 0 && threadIdx.x == 0) offs[N] = E;
}

__global__ void k_dinv(const int* __restrict__ counts, int N, float* __restrict__ dinv) {
    int i = blockIdx.x * blockDim.x + threadIdx.x;
    if (i < N) dinv[i] = rsqrtf((float)(counts[i] + 1));  // +1 = self loop
}

__global__ void k_fill(const int* __restrict__ src, const int* __restrict__ dst, int E,
                       int* __restrict__ cursor, int* __restrict__ ssrc) {
    int e = blockIdx.x * blockDim.x + threadIdx.x;
    if (e < E) {
        int p = atomicAdd(&cursor[dst[e]], 1);
        ssrc[p] = src[e];
    }
}

// ---------------- dense transform: C[N,M] = A[N,K] @ W[K,M] (fp32 SIMT, LDS-tiled) ----------------

template <int K, int M>
__global__ __launch_bounds__(256) void k_gemm(const float* __restrict__ A,
                                              const float* __restrict__ W,
                                              float* __restrict__ C, int N) {
    constexpr int KC = 64;
    constexpr int CPT = M / 16;                 // cols per thread: 8 (M=128) or 4 (M=64)
    __shared__ float As[64][KC + 4];            // +4 keeps float4 alignment, breaks bank aliasing
    __shared__ float Ws[KC][M];
    const int t = threadIdx.x;
    const int tx = t & 15;
    const int ty = t >> 4;
    const int row0 = blockIdx.x * 64;

    float acc[4][CPT];
#pragma unroll
    for (int i = 0; i < 4; i++)
#pragma unroll
        for (int j = 0; j < CPT; j++) acc[i][j] = 0.f;

    for (int kc = 0; kc < K; kc += KC) {
        // stage A tile: 64 rows x KC cols
#pragma unroll
        for (int i = 0; i < 4; i++) {
            int idx = i * 256 + t;              // 0..1023 float4 slots
            int r = idx >> 4;
            int kk = (idx & 15) << 2;
            int gr = row0 + r;
            float4 v = make_float4(0.f, 0.f, 0.f, 0.f);
            if (gr < N) v = *(const float4*)&A[(size_t)gr * K + kc + kk];
            *(float4*)&As[r][kk] = v;
        }
        // stage W tile: KC x M
#pragma unroll
        for (int i = 0; i < CPT; i++) {
            int idx = i * 256 + t;
            int kk = idx / (M / 4);
            int c = (idx % (M / 4)) << 2;
            *(float4*)&Ws[kk][c] = *(const float4*)&W[(size_t)(kc + kk) * M + c];
        }
        __syncthreads();

#pragma unroll 2
        for (int k = 0; k < KC; k += 4) {
            float4 a4[4];
#pragma unroll
            for (int i = 0; i < 4; i++) a4[i] = *(const float4*)&As[ty * 4 + i][k];
#pragma unroll
            for (int kk = 0; kk < 4; kk++) {
                float w[CPT];
#pragma unroll
                for (int j = 0; j < CPT; j += 4) {
                    float4 wv = *(const float4*)&Ws[k + kk][tx * CPT + j];
                    w[j] = wv.x; w[j + 1] = wv.y; w[j + 2] = wv.z; w[j + 3] = wv.w;
                }
#pragma unroll
                for (int i = 0; i < 4; i++) {
                    float a = ((const float*)&a4[i])[kk];
#pragma unroll
                    for (int j = 0; j < CPT; j++) acc[i][j] = fmaf(a, w[j], acc[i][j]);
                }
            }
        }
        __syncthreads();
    }

#pragma unroll
    for (int i = 0; i < 4; i++) {
        int gr = row0 + ty * 4 + i;
        if (gr < N) {
#pragma unroll
            for (int j = 0; j < CPT; j += 4) {
                float4 v = make_float4(acc[i][j], acc[i][j + 1], acc[i][j + 2], acc[i][j + 3]);
                *(float4*)&C[(size_t)gr * M + tx * CPT + j] = v;
            }
        }
    }
}

// ---------------- aggregate: out[n] = relu(sum_{e: dst=n} norm*h[src] + dinv[n]^2*h[n] + b) ----------------
// one wave per node; FINAL fuses log_softmax over 64 features

template <int M, bool FINAL>
__global__ __launch_bounds__(256) void k_agg(const float* __restrict__ tmat,
                                             const int* __restrict__ offs,
                                             const int* __restrict__ ssrc,
                                             const float* __restrict__ dinv,
                                             const float* __restrict__ bias,
                                             float* __restrict__ out, int N) {
    constexpr int F = M / 64;
    int wid = (int)(((size_t)blockIdx.x * blockDim.x + threadIdx.x) >> 6);
    int lane = threadIdx.x & 63;
    if (wid >= N) return;
    const int n = wid;
    const float dn = dinv[n];
    float acc[F];
#pragma unroll
    for (int f = 0; f < F; f++)
        acc[f] = dn * dn * tmat[(size_t)n * M + f * 64 + lane];   // self-loop
    const int e0 = offs[n], e1 = offs[n + 1];
    for (int j = e0; j < e1; ++j) {
        int s = ssrc[j];
        float nr = dinv[s] * dn;
#pragma unroll
        for (int f = 0; f < F; f++)
            acc[f] = fmaf(nr, tmat[(size_t)s * M + f * 64 + lane], acc[f]);
    }
    if (!FINAL) {
#pragma unroll
        for (int f = 0; f < F; f++) {
            float v = acc[f] + bias[f * 64 + lane];
            out[(size_t)n * M + f * 64 + lane] = fmaxf(v, 0.f);
        }
    } else {
        float v = fmaxf(acc[0] + bias[lane], 0.f);
        float m = v;
#pragma unroll
        for (int d = 1; d < 64; d <<= 1) m = fmaxf(m, __shfl_xor(m, d));
        float ex = expf(v - m);
        float ssum = ex;
#pragma unroll
        for (int d = 1; d < 64; d <<= 1) ssum += __shfl_xor(ssum, d);
        out[(size_t)n * 64 + lane] = v - m - logf(ssum);
    }
}

// ---------------- launcher ----------------

extern "C" void kernel_launch(void* const* d_in, const int* in_sizes, int n_in,
                              void* d_out, int out_size, void* d_ws, size_t ws_size,
                              hipStream_t stream) {
    const float* x  = (const float*)d_in[0];
    const int*   ei = (const int*)d_in[1];
    const float* W1 = (const float*)d_in[2];
    const float* b1 = (const float*)d_in[3];
    const float* W2 = (const float*)d_in[4];
    const float* b2 = (const float*)d_in[5];
    const float* W3 = (const float*)d_in[6];
    const float* b3 = (const float*)d_in[7];
    const float* W4 = (const float*)d_in[8];
    const float* b4 = (const float*)d_in[9];

    const int N = in_sizes[0] / IN_DIM;   // 100000
    const int E = in_sizes[1] / 2;        // 1600000
    const int* src = ei;
    const int* dst = ei + E;

    char* p = (char*)d_ws;
    float* bufA = (float*)p;  p += (size_t)N * HID * sizeof(float);
    float* bufB = (float*)p;  p += (size_t)N * HID * sizeof(float);
    float* dinv = (float*)p;  p += (size_t)N * sizeof(float);
    int* counts = (int*)p;    p += (size_t)N * sizeof(int);
    int* offs   = (int*)p;    p += (size_t)(N + 1) * sizeof(int);
    int* cursor = (int*)p;    p += (size_t)N * sizeof(int);
    int* bsums  = (int*)p;    p += 256 * sizeof(int);
    int* ssrc   = (int*)p;    p += (size_t)E * sizeof(int);

    hipMemsetAsync(counts, 0, (size_t)N * sizeof(int), stream);

    const int eb = (E + 255) / 256;
    const int nb = (N + 1023) / 1024;
    k_hist<<<eb, 256, 0, stream>>>(dst, E, counts);
    k_scan1<<<nb, 1024, 0, stream>>>(counts, N, offs, bsums);
    k_scan2<<<1, 256, 0, stream>>>(bsums, nb);
    k_scan3<<<nb, 1024, 0, stream>>>(offs, bsums, N, E, cursor);
    k_dinv<<<(N + 255) / 256, 256, 0, stream>>>(counts, N, dinv);
    k_fill<<<eb, 256, 0, stream>>>(src, dst, E, cursor, ssrc);

    const int gb = (N + 63) / 64;
    const int ab = (N + 3) / 4;
    k_gemm<IN_DIM, HID><<<gb, 256, 0, stream>>>(x, W1, bufA, N);
    k_agg<HID, false><<<ab, 256, 0, stream>>>(bufA, offs, ssrc, dinv, b1, bufB, N);
    k_gemm<HID, HID><<<gb, 256, 0, stream>>>(bufB, W2, bufA, N);
    k_agg<HID, false><<<ab, 256, 0, stream>>>(bufA, offs, ssrc, dinv, b2, bufB, N);
    k_gemm<HID, HID><<<gb, 256, 0, stream>>>(bufB, W3, bufA, N);
    k_agg<HID, false><<<ab, 256, 0, stream>>>(bufA, offs, ssrc, dinv, b3, bufB, N);
    k_gemm<HID, OUT_DIM><<<gb, 256, 0, stream>>>(bufB, W4, bufA, N);
    k_agg<OUT_DIM, true><<<ab, 256, 0, stream>>>(bufA, offs, ssrc, dinv, b4, (float*)d_out, N);
}

// Round 2
// 1080.786 us; speedup vs baseline: 1.1125x; 1.1125x over previous
//
#include <hip/hip_runtime.h>
#include <cstdint>
#include <cstddef>

static constexpr int IN_DIM = 512;
static constexpr int HID = 128;
static constexpr int OUT_DIM = 64;

typedef __attribute__((ext_vector_type(8))) short bf16x8;
typedef __attribute__((ext_vector_type(4))) float f32x4;

__device__ inline unsigned short f2bf(float x) {
    unsigned u = __float_as_uint(x);
    unsigned r = (u + 0x7FFFu + ((u >> 16) & 1u)) >> 16;
    return (unsigned short)r;
}
__device__ inline float bf2f(unsigned short b) { return __uint_as_float(((unsigned)b) << 16); }

// ---------------- CSR construction (counting sort by dst, rebuilt every call) ----------------

__global__ void k_hist(const int* __restrict__ dst, int E, int* __restrict__ counts) {
    int e = blockIdx.x * blockDim.x + threadIdx.x;
    if (e < E) atomicAdd(&counts[dst[e]], 1);
}

__global__ void k_scan1(const int* __restrict__ counts, int N, int* __restrict__ offs,
                        int* __restrict__ bsums) {
    __shared__ int sm[1024];
    int i = blockIdx.x * 1024 + threadIdx.x;
    int v = (i < N) ? counts[i] : 0;
    sm[threadIdx.x] = v;
    __syncthreads();
    for (int d = 1; d < 1024; d <<= 1) {
        int t = (threadIdx.x >= d) ? sm[threadIdx.x - d] : 0;
        __syncthreads();
        sm[threadIdx.x] += t;
        __syncthreads();
    }
    if (i < N) offs[i] = sm[threadIdx.x] - v;
    if (threadIdx.x == 1023) bsums[blockIdx.x] = sm[1023];
}

__global__ void k_scan2(int* __restrict__ bsums, int nb) {
    __shared__ int sm[256];
    int x = threadIdx.x;
    int v = (x < nb) ? bsums[x] : 0;
    sm[x] = v;
    __syncthreads();
    for (int d = 1; d < 256; d <<= 1) {
        int t = (x >= d) ? sm[x - d] : 0;
        __syncthreads();
        sm[x] += t;
        __syncthreads();
    }
    if (x < nb) bsums[x] = sm[x] - v;
}

__global__ void k_scan3(int* __restrict__ offs, const int* __restrict__ bsums, int N, int E,
                        int* __restrict__ cursor) {
    int i = blockIdx.x * 1024 + threadIdx.x;
    if (i < N) {
        int o = offs[i] + bsums[blockIdx.x];
        offs[i] = o;
        cursor[i] = o;
    }
    if (blockIdx.x == 0 && threadIdx.x == 0) offs[N] = E;
}

__global__ void k_dinv(const int* __restrict__ counts, int N, float* __restrict__ dinv) {
    int i = blockIdx.x * blockDim.x + threadIdx.x;
    if (i < N) dinv[i] = rsqrtf((float)(counts[i] + 1));
}

__global__ void k_fill(const int* __restrict__ src, const int* __restrict__ dst, int E,
                       int* __restrict__ cursor, int* __restrict__ ssrc) {
    int e = blockIdx.x * blockDim.x + threadIdx.x;
    if (e < E) {
        int p = atomicAdd(&cursor[dst[e]], 1);
        ssrc[p] = src[e];
    }
}

// ---------------- W split+repack into MFMA B-fragment order ----------------
// layout: idx = ((f*(K/32) + kg)*64 + lane)*8 + j ; lane: col = f*16 + (lane&15),
// k = kg*32 + (lane>>4)*8 + j

__global__ void k_splitW(const float* __restrict__ W, int K, int M,
                         unsigned short* __restrict__ whi, unsigned short* __restrict__ wlo) {
    int idx = blockIdx.x * 256 + threadIdx.x;
    int total = K * M;
    if (idx >= total) return;
    int j = idx & 7;
    int l = (idx >> 3) & 63;
    int rest = idx >> 9;
    int KG = K >> 5;
    int kg = rest % KG;
    int f = rest / KG;
    int c = l & 15, g = l >> 4;
    int k = kg * 32 + g * 8 + j;
    int col = f * 16 + c;
    float v = W[(size_t)k * M + col];
    unsigned short h = f2bf(v);
    whi[idx] = h;
    wlo[idx] = f2bf(v - bf2f(h));
}

// ---------------- GEMM: C[N,M] = A[N,K] @ W[K,M], split-bf16 MFMA, LDS-free ----------------
// block = 256 thr = 4 waves; block tile 128 rows x M cols; wave tile 32 x M.

template <int K, int M>
__global__ __launch_bounds__(256) void k_gemm_mfma(const float* __restrict__ A,
                                                   const unsigned short* __restrict__ whi,
                                                   const unsigned short* __restrict__ wlo,
                                                   float* __restrict__ C, int N) {
    constexpr int NF = M / 16;
    constexpr int KG = K / 32;
    const int wave = threadIdx.x >> 6;
    const int lane = threadIdx.x & 63;
    const int c = lane & 15, g = lane >> 4;
    const int r0 = blockIdx.x * 128 + wave * 32;

    f32x4 acc[2][NF];
#pragma unroll
    for (int m = 0; m < 2; m++)
#pragma unroll
        for (int f = 0; f < NF; f++) acc[m][f] = (f32x4){0.f, 0.f, 0.f, 0.f};

    // A fragment rows (clamped for tail blocks; stores are guarded)
    const int rA0 = min(r0 + c, N - 1);
    const int rA1 = min(r0 + 16 + c, N - 1);
    const float* ap0 = A + (size_t)rA0 * K + g * 8;
    const float* ap1 = A + (size_t)rA1 * K + g * 8;

    for (int kg = 0; kg < KG; ++kg) {
        float av0[8], av1[8];
        *(float4*)&av0[0] = *(const float4*)(ap0 + kg * 32);
        *(float4*)&av0[4] = *(const float4*)(ap0 + kg * 32 + 4);
        *(float4*)&av1[0] = *(const float4*)(ap1 + kg * 32);
        *(float4*)&av1[4] = *(const float4*)(ap1 + kg * 32 + 4);

        bf16x8 ah0, al0, ah1, al1;
#pragma unroll
        for (int j = 0; j < 8; ++j) {
            unsigned short h0 = f2bf(av0[j]);
            unsigned short h1 = f2bf(av1[j]);
            ah0[j] = (short)h0;
            ah1[j] = (short)h1;
            al0[j] = (short)f2bf(av0[j] - bf2f(h0));
            al1[j] = (short)f2bf(av1[j] - bf2f(h1));
        }

#pragma unroll
        for (int f = 0; f < NF; ++f) {
            size_t boff = ((size_t)(f * KG + kg) * 64 + lane) * 8;
            bf16x8 bh = *(const bf16x8*)(whi + boff);
            bf16x8 bl = *(const bf16x8*)(wlo + boff);
            acc[0][f] = __builtin_amdgcn_mfma_f32_16x16x32_bf16(al0, bh, acc[0][f], 0, 0, 0);
            acc[0][f] = __builtin_amdgcn_mfma_f32_16x16x32_bf16(ah0, bl, acc[0][f], 0, 0, 0);
            acc[0][f] = __builtin_amdgcn_mfma_f32_16x16x32_bf16(ah0, bh, acc[0][f], 0, 0, 0);
            acc[1][f] = __builtin_amdgcn_mfma_f32_16x16x32_bf16(al1, bh, acc[1][f], 0, 0, 0);
            acc[1][f] = __builtin_amdgcn_mfma_f32_16x16x32_bf16(ah1, bl, acc[1][f], 0, 0, 0);
            acc[1][f] = __builtin_amdgcn_mfma_f32_16x16x32_bf16(ah1, bh, acc[1][f], 0, 0, 0);
        }
    }

    // C/D layout: col = lane&15, row = (lane>>4)*4 + reg
#pragma unroll
    for (int m = 0; m < 2; m++) {
        int rb = r0 + m * 16 + g * 4;
#pragma unroll
        for (int reg = 0; reg < 4; reg++) {
            int row = rb + reg;
            if (row < N) {
#pragma unroll
                for (int f = 0; f < NF; f++)
                    C[(size_t)row * M + f * 16 + c] = acc[m][f][reg];
            }
        }
    }
}

// ---------------- aggregate (M=128): out[n] = relu(sum norm*h[src] + self + b), float2/lane ----

__global__ __launch_bounds__(256) void k_agg128(const float* __restrict__ tmat,
                                                const int* __restrict__ offs,
                                                const int* __restrict__ ssrc,
                                                const float* __restrict__ dinv,
                                                const float* __restrict__ bias,
                                                float* __restrict__ out, int N) {
    int wid = (int)(((size_t)blockIdx.x * blockDim.x + threadIdx.x) >> 6);
    int lane = threadIdx.x & 63;
    if (wid >= N) return;
    const int n = wid;
    const float dn = dinv[n];
    const float2* tm = (const float2*)tmat;   // row stride = 64 float2
    float2 t = tm[(size_t)n * 64 + lane];
    float ax = dn * dn * t.x, ay = dn * dn * t.y;
    const int e0 = offs[n], e1 = offs[n + 1];
    for (int j = e0; j < e1; ++j) {
        int s = ssrc[j];
        float nr = dinv[s] * dn;
        float2 v = tm[(size_t)s * 64 + lane];
        ax = fmaf(nr, v.x, ax);
        ay = fmaf(nr, v.y, ay);
    }
    float2 b = ((const float2*)bias)[lane];
    float2 o;
    o.x = fmaxf(ax + b.x, 0.f);
    o.y = fmaxf(ay + b.y, 0.f);
    ((float2*)out)[(size_t)n * 64 + lane] = o;
}

// ---------------- final aggregate (M=64) + log_softmax ----------------

__global__ __launch_bounds__(256) void k_agg64f(const float* __restrict__ tmat,
                                                const int* __restrict__ offs,
                                                const int* __restrict__ ssrc,
                                                const float* __restrict__ dinv,
                                                const float* __restrict__ bias,
                                                float* __restrict__ out, int N) {
    int wid = (int)(((size_t)blockIdx.x * blockDim.x + threadIdx.x) >> 6);
    int lane = threadIdx.x & 63;
    if (wid >= N) return;
    const int n = wid;
    const float dn = dinv[n];
    float acc = dn * dn * tmat[(size_t)n * 64 + lane];
    const int e0 = offs[n], e1 = offs[n + 1];
    for (int j = e0; j < e1; ++j) {
        int s = ssrc[j];
        acc = fmaf(dinv[s] * dn, tmat[(size_t)s * 64 + lane], acc);
    }
    float v = fmaxf(acc + bias[lane], 0.f);
    float m = v;
#pragma unroll
    for (int d = 1; d < 64; d <<= 1) m = fmaxf(m, __shfl_xor(m, d));
    float ex = expf(v - m);
    float ssum = ex;
#pragma unroll
    for (int d = 1; d < 64; d <<= 1) ssum += __shfl_xor(ssum, d);
    out[(size_t)n * 64 + lane] = v - m - logf(ssum);
}

// ---------------- launcher ----------------

extern "C" void kernel_launch(void* const* d_in, const int* in_sizes, int n_in,
                              void* d_out, int out_size, void* d_ws, size_t ws_size,
                              hipStream_t stream) {
    const float* x  = (const float*)d_in[0];
    const int*   ei = (const int*)d_in[1];
    const float* W1 = (const float*)d_in[2];
    const float* b1 = (const float*)d_in[3];
    const float* W2 = (const float*)d_in[4];
    const float* b2 = (const float*)d_in[5];
    const float* W3 = (const float*)d_in[6];
    const float* b3 = (const float*)d_in[7];
    const float* W4 = (const float*)d_in[8];
    const float* b4 = (const float*)d_in[9];

    const int N = in_sizes[0] / IN_DIM;   // 100000
    const int E = in_sizes[1] / 2;        // 1600000
    const int* src = ei;
    const int* dst = ei + E;

    char* p = (char*)d_ws;
    float* bufA = (float*)p;  p += (size_t)N * HID * sizeof(float);
    float* bufB = (float*)p;  p += (size_t)N * HID * sizeof(float);
    float* dinv = (float*)p;  p += (size_t)N * sizeof(float);
    int* counts = (int*)p;    p += (size_t)N * sizeof(int);
    int* offs   = (int*)p;    p += (size_t)(N + 1) * sizeof(int);
    int* cursor = (int*)p;    p += (size_t)N * sizeof(int);
    int* bsums  = (int*)p;    p += 256 * sizeof(int);
    int* ssrc   = (int*)p;    p += (size_t)E * sizeof(int);
    unsigned short* w1h = (unsigned short*)p; p += (size_t)IN_DIM * HID * 2;
    unsigned short* w1l = (unsigned short*)p; p += (size_t)IN_DIM * HID * 2;
    unsigned short* w2h = (unsigned short*)p; p += (size_t)HID * HID * 2;
    unsigned short* w2l = (unsigned short*)p; p += (size_t)HID * HID * 2;
    unsigned short* w3h = (unsigned short*)p; p += (size_t)HID * HID * 2;
    unsigned short* w3l = (unsigned short*)p; p += (size_t)HID * HID * 2;
    unsigned short* w4h = (unsigned short*)p; p += (size_t)HID * OUT_DIM * 2;
    unsigned short* w4l = (unsigned short*)p; p += (size_t)HID * OUT_DIM * 2;

    hipMemsetAsync(counts, 0, (size_t)N * sizeof(int), stream);

    const int eb = (E + 255) / 256;
    const int nb = (N + 1023) / 1024;
    k_hist<<<eb, 256, 0, stream>>>(dst, E, counts);
    k_scan1<<<nb, 1024, 0, stream>>>(counts, N, offs, bsums);
    k_scan2<<<1, 256, 0, stream>>>(bsums, nb);
    k_scan3<<<nb, 1024, 0, stream>>>(offs, bsums, N, E, cursor);
    k_dinv<<<(N + 255) / 256, 256, 0, stream>>>(counts, N, dinv);
    k_fill<<<eb, 256, 0, stream>>>(src, dst, E, cursor, ssrc);

    k_splitW<<<(IN_DIM * HID + 255) / 256, 256, 0, stream>>>(W1, IN_DIM, HID, w1h, w1l);
    k_splitW<<<(HID * HID + 255) / 256, 256, 0, stream>>>(W2, HID, HID, w2h, w2l);
    k_splitW<<<(HID * HID + 255) / 256, 256, 0, stream>>>(W3, HID, HID, w3h, w3l);
    k_splitW<<<(HID * OUT_DIM + 255) / 256, 256, 0, stream>>>(W4, HID, OUT_DIM, w4h, w4l);

    const int gb = (N + 127) / 128;
    const int ab = (N + 3) / 4;
    k_gemm_mfma<IN_DIM, HID><<<gb, 256, 0, stream>>>(x, w1h, w1l, bufA, N);
    k_agg128<<<ab, 256, 0, stream>>>(bufA, offs, ssrc, dinv, b1, bufB, N);
    k_gemm_mfma<HID, HID><<<gb, 256, 0, stream>>>(bufB, w2h, w2l, bufA, N);
    k_agg128<<<ab, 256, 0, stream>>>(bufA, offs, ssrc, dinv, b2, bufB, N);
    k_gemm_mfma<HID, HID><<<gb, 256, 0, stream>>>(bufB, w3h, w3l, bufA, N);
    k_agg128<<<ab, 256, 0, stream>>>(bufA, offs, ssrc, dinv, b3, bufB, N);
    k_gemm_mfma<HID, OUT_DIM><<<gb, 256, 0, stream>>>(bufB, w4h, w4l, bufA, N);
    k_agg64f<<<ab, 256, 0, stream>>>(bufA, offs, ssrc, dinv, b4, (float*)d_out, N);
}

// Round 3
// 708.190 us; speedup vs baseline: 1.6978x; 1.5261x over previous
//
#include <hip/hip_runtime.h>
#include <cstdint>
#include <cstddef>

static constexpr int IN_DIM = 512;
static constexpr int HID = 128;
static constexpr int OUT_DIM = 64;

typedef __attribute__((ext_vector_type(8))) short bf16x8;
typedef __attribute__((ext_vector_type(4))) float f32x4;

__device__ inline unsigned short f2bf(float x) {
    unsigned u = __float_as_uint(x);
    unsigned r = (u + 0x7FFFu + ((u >> 16) & 1u)) >> 16;   // RNE
    return (unsigned short)r;
}
__device__ inline float bf2f(unsigned short b) { return __uint_as_float(((unsigned)b) << 16); }
__device__ inline float bflo(unsigned u) { return __uint_as_float(u << 16); }
__device__ inline float bfhi(unsigned u) { return __uint_as_float(u & 0xFFFF0000u); }

// ---------------- CSR construction (counting sort by dst, rebuilt every call) ----------------

__global__ void k_hist(const int* __restrict__ dst, int E, int* __restrict__ counts) {
    int e = blockIdx.x * blockDim.x + threadIdx.x;
    if (e < E) atomicAdd(&counts[dst[e]], 1);
}

__global__ void k_scan1(const int* __restrict__ counts, int N, int* __restrict__ offs,
                        int* __restrict__ bsums) {
    __shared__ int sm[1024];
    int i = blockIdx.x * 1024 + threadIdx.x;
    int v = (i < N) ? counts[i] : 0;
    sm[threadIdx.x] = v;
    __syncthreads();
    for (int d = 1; d < 1024; d <<= 1) {
        int t = (threadIdx.x >= d) ? sm[threadIdx.x - d] : 0;
        __syncthreads();
        sm[threadIdx.x] += t;
        __syncthreads();
    }
    if (i < N) offs[i] = sm[threadIdx.x] - v;
    if (threadIdx.x == 1023) bsums[blockIdx.x] = sm[1023];
}

__global__ void k_scan2(int* __restrict__ bsums, int nb) {
    __shared__ int sm[256];
    int x = threadIdx.x;
    int v = (x < nb) ? bsums[x] : 0;
    sm[x] = v;
    __syncthreads();
    for (int d = 1; d < 256; d <<= 1) {
        int t = (x >= d) ? sm[x - d] : 0;
        __syncthreads();
        sm[x] += t;
        __syncthreads();
    }
    if (x < nb) bsums[x] = sm[x] - v;
}

__global__ void k_scan3(int* __restrict__ offs, const int* __restrict__ bsums, int N, int E,
                        int* __restrict__ cursor) {
    int i = blockIdx.x * 1024 + threadIdx.x;
    if (i < N) {
        int o = offs[i] + bsums[blockIdx.x];
        offs[i] = o;
        cursor[i] = o;
    }
    if (blockIdx.x == 0 && threadIdx.x == 0) offs[N] = E;
}

__global__ void k_dinv(const int* __restrict__ counts, int N, float* __restrict__ dinv) {
    int i = blockIdx.x * blockDim.x + threadIdx.x;
    if (i < N) dinv[i] = rsqrtf((float)(counts[i] + 1));
}

__global__ void k_fill(const int* __restrict__ src, const int* __restrict__ dst, int E,
                       int* __restrict__ cursor, int* __restrict__ ssrc) {
    int e = blockIdx.x * blockDim.x + threadIdx.x;
    if (e < E) {
        int p = atomicAdd(&cursor[dst[e]], 1);
        ssrc[p] = src[e];
    }
}

// ---------------- W split+repack into MFMA B-fragment order ----------------

__global__ void k_splitW(const float* __restrict__ W, int K, int M,
                         unsigned short* __restrict__ whi, unsigned short* __restrict__ wlo) {
    int idx = blockIdx.x * 256 + threadIdx.x;
    int total = K * M;
    if (idx >= total) return;
    int j = idx & 7;
    int l = (idx >> 3) & 63;
    int rest = idx >> 9;
    int KG = K >> 5;
    int kg = rest % KG;
    int f = rest / KG;
    int c = l & 15, g = l >> 4;
    int k = kg * 32 + g * 8 + j;
    int col = f * 16 + c;
    float v = W[(size_t)k * M + col];
    unsigned short h = f2bf(v);
    whi[idx] = h;
    wlo[idx] = f2bf(v - bf2f(h));
}

// ---------------- GEMM: C = dinv ⊙ (A[N,K] @ W[K,M]); split-bf16 MFMA, LDS-free ----------------
// output scaled by dinv[row]; BF16OUT stores bf16 (layers 1-3), else fp32 (final layer)

template <int K, int M, bool BF16OUT>
__global__ __launch_bounds__(256) void k_gemm_mfma(const float* __restrict__ A,
                                                   const unsigned short* __restrict__ whi,
                                                   const unsigned short* __restrict__ wlo,
                                                   const float* __restrict__ dinv,
                                                   void* __restrict__ Cout, int N) {
    constexpr int NF = M / 16;
    constexpr int KG = K / 32;
    const int wave = threadIdx.x >> 6;
    const int lane = threadIdx.x & 63;
    const int c = lane & 15, g = lane >> 4;
    const int r0 = blockIdx.x * 128 + wave * 32;

    f32x4 acc[2][NF];
#pragma unroll
    for (int m = 0; m < 2; m++)
#pragma unroll
        for (int f = 0; f < NF; f++) acc[m][f] = (f32x4){0.f, 0.f, 0.f, 0.f};

    const int rA0 = min(r0 + c, N - 1);
    const int rA1 = min(r0 + 16 + c, N - 1);
    const float* ap0 = A + (size_t)rA0 * K + g * 8;
    const float* ap1 = A + (size_t)rA1 * K + g * 8;

    for (int kg = 0; kg < KG; ++kg) {
        float av0[8], av1[8];
        *(float4*)&av0[0] = *(const float4*)(ap0 + kg * 32);
        *(float4*)&av0[4] = *(const float4*)(ap0 + kg * 32 + 4);
        *(float4*)&av1[0] = *(const float4*)(ap1 + kg * 32);
        *(float4*)&av1[4] = *(const float4*)(ap1 + kg * 32 + 4);

        bf16x8 ah0, al0, ah1, al1;
#pragma unroll
        for (int j = 0; j < 8; ++j) {
            unsigned short h0 = f2bf(av0[j]);
            unsigned short h1 = f2bf(av1[j]);
            ah0[j] = (short)h0;
            ah1[j] = (short)h1;
            al0[j] = (short)f2bf(av0[j] - bf2f(h0));
            al1[j] = (short)f2bf(av1[j] - bf2f(h1));
        }

#pragma unroll
        for (int f = 0; f < NF; ++f) {
            size_t boff = ((size_t)(f * KG + kg) * 64 + lane) * 8;
            bf16x8 bh = *(const bf16x8*)(whi + boff);
            bf16x8 bl = *(const bf16x8*)(wlo + boff);
            acc[0][f] = __builtin_amdgcn_mfma_f32_16x16x32_bf16(al0, bh, acc[0][f], 0, 0, 0);
            acc[0][f] = __builtin_amdgcn_mfma_f32_16x16x32_bf16(ah0, bl, acc[0][f], 0, 0, 0);
            acc[0][f] = __builtin_amdgcn_mfma_f32_16x16x32_bf16(ah0, bh, acc[0][f], 0, 0, 0);
            acc[1][f] = __builtin_amdgcn_mfma_f32_16x16x32_bf16(al1, bh, acc[1][f], 0, 0, 0);
            acc[1][f] = __builtin_amdgcn_mfma_f32_16x16x32_bf16(ah1, bl, acc[1][f], 0, 0, 0);
            acc[1][f] = __builtin_amdgcn_mfma_f32_16x16x32_bf16(ah1, bh, acc[1][f], 0, 0, 0);
        }
    }

    // C/D layout: col = lane&15, row = (lane>>4)*4 + reg
#pragma unroll
    for (int m = 0; m < 2; m++) {
        int rb = r0 + m * 16 + g * 4;
#pragma unroll
        for (int reg = 0; reg < 4; reg++) {
            int row = rb + reg;
            if (row < N) {
                float sc = dinv[row];
                if (BF16OUT) {
                    unsigned short* Cb = (unsigned short*)Cout;
#pragma unroll
                    for (int f = 0; f < NF; f++)
                        Cb[(size_t)row * M + f * 16 + c] = f2bf(acc[m][f][reg] * sc);
                } else {
                    float* Cf = (float*)Cout;
#pragma unroll
                    for (int f = 0; f < NF; f++)
                        Cf[(size_t)row * M + f * 16 + c] = acc[m][f][reg] * sc;
                }
            }
        }
    }
}

// ---------------- aggregate (M=128, bf16 rows): out = relu(dn*(g[n]+Σ g[src]) + b) ----------------
// g rows pre-scaled by dinv; one wave per node; per lane one uint = 2 bf16 features

__global__ __launch_bounds__(256) void k_aggbf(const unsigned* __restrict__ g,
                                               const int* __restrict__ offs,
                                               const int* __restrict__ ssrc,
                                               const float* __restrict__ dinv,
                                               const float* __restrict__ bias,
                                               float* __restrict__ out, int N) {
    int wid = (int)(((size_t)blockIdx.x * blockDim.x + threadIdx.x) >> 6);
    int lane = threadIdx.x & 63;
    if (wid >= N) return;
    const int n = wid;
    const float dn = dinv[n];
    unsigned u = g[(size_t)n * 64 + lane];          // self (g already dinv-scaled)
    float ax = bflo(u), ay = bfhi(u);
    const int e0 = offs[n], e1 = offs[n + 1];
    int j = e0;
    for (; j + 4 <= e1; j += 4) {
        int s0 = ssrc[j], s1 = ssrc[j + 1], s2 = ssrc[j + 2], s3 = ssrc[j + 3];
        unsigned u0 = g[(size_t)s0 * 64 + lane];
        unsigned u1 = g[(size_t)s1 * 64 + lane];
        unsigned u2 = g[(size_t)s2 * 64 + lane];
        unsigned u3 = g[(size_t)s3 * 64 + lane];
        ax += bflo(u0); ay += bfhi(u0);
        ax += bflo(u1); ay += bfhi(u1);
        ax += bflo(u2); ay += bfhi(u2);
        ax += bflo(u3); ay += bfhi(u3);
    }
    for (; j < e1; ++j) {
        unsigned uu = g[(size_t)ssrc[j] * 64 + lane];
        ax += bflo(uu); ay += bfhi(uu);
    }
    float2 b = ((const float2*)bias)[lane];
    float2 o;
    o.x = fmaxf(fmaf(dn, ax, b.x), 0.f);
    o.y = fmaxf(fmaf(dn, ay, b.y), 0.f);
    ((float2*)out)[(size_t)n * 64 + lane] = o;
}

// ---------------- final aggregate (M=64, fp32 rows) + log_softmax ----------------

__global__ __launch_bounds__(256) void k_agg64f(const float* __restrict__ g,
                                                const int* __restrict__ offs,
                                                const int* __restrict__ ssrc,
                                                const float* __restrict__ dinv,
                                                const float* __restrict__ bias,
                                                float* __restrict__ out, int N) {
    int wid = (int)(((size_t)blockIdx.x * blockDim.x + threadIdx.x) >> 6);
    int lane = threadIdx.x & 63;
    if (wid >= N) return;
    const int n = wid;
    const float dn = dinv[n];
    float acc = g[(size_t)n * 64 + lane];
    const int e0 = offs[n], e1 = offs[n + 1];
    int j = e0;
    for (; j + 4 <= e1; j += 4) {
        int s0 = ssrc[j], s1 = ssrc[j + 1], s2 = ssrc[j + 2], s3 = ssrc[j + 3];
        float v0 = g[(size_t)s0 * 64 + lane];
        float v1 = g[(size_t)s1 * 64 + lane];
        float v2 = g[(size_t)s2 * 64 + lane];
        float v3 = g[(size_t)s3 * 64 + lane];
        acc += v0 + v1 + v2 + v3;
    }
    for (; j < e1; ++j) acc += g[(size_t)ssrc[j] * 64 + lane];
    float v = fmaxf(fmaf(dn, acc, bias[lane]), 0.f);
    float m = v;
#pragma unroll
    for (int d = 1; d < 64; d <<= 1) m = fmaxf(m, __shfl_xor(m, d));
    float ex = expf(v - m);
    float ssum = ex;
#pragma unroll
    for (int d = 1; d < 64; d <<= 1) ssum += __shfl_xor(ssum, d);
    out[(size_t)n * 64 + lane] = v - m - logf(ssum);
}

// ---------------- launcher ----------------

extern "C" void kernel_launch(void* const* d_in, const int* in_sizes, int n_in,
                              void* d_out, int out_size, void* d_ws, size_t ws_size,
                              hipStream_t stream) {
    const float* x  = (const float*)d_in[0];
    const int*   ei = (const int*)d_in[1];
    const float* W1 = (const float*)d_in[2];
    const float* b1 = (const float*)d_in[3];
    const float* W2 = (const float*)d_in[4];
    const float* b2 = (const float*)d_in[5];
    const float* W3 = (const float*)d_in[6];
    const float* b3 = (const float*)d_in[7];
    const float* W4 = (const float*)d_in[8];
    const float* b4 = (const float*)d_in[9];

    const int N = in_sizes[0] / IN_DIM;   // 100000
    const int E = in_sizes[1] / 2;        // 1600000
    const int* src = ei;
    const int* dst = ei + E;

    char* p = (char*)d_ws;
    float* afp = (float*)p;           p += (size_t)N * HID * sizeof(float);   // agg out (fp32)
    unsigned short* hbf = (unsigned short*)p; p += (size_t)N * HID * 2;       // gemm out (bf16)
    float* h4  = (float*)p;           p += (size_t)N * OUT_DIM * sizeof(float); // gemm4 out
    float* dinv = (float*)p;          p += (size_t)N * sizeof(float);
    int* counts = (int*)p;            p += (size_t)N * sizeof(int);
    int* offs   = (int*)p;            p += (size_t)(N + 1) * sizeof(int);
    int* cursor = (int*)p;            p += (size_t)N * sizeof(int);
    int* bsums  = (int*)p;            p += 256 * sizeof(int);
    int* ssrc   = (int*)p;            p += (size_t)E * sizeof(int);
    unsigned short* w1h = (unsigned short*)p; p += (size_t)IN_DIM * HID * 2;
    unsigned short* w1l = (unsigned short*)p; p += (size_t)IN_DIM * HID * 2;
    unsigned short* w2h = (unsigned short*)p; p += (size_t)HID * HID * 2;
    unsigned short* w2l = (unsigned short*)p; p += (size_t)HID * HID * 2;
    unsigned short* w3h = (unsigned short*)p; p += (size_t)HID * HID * 2;
    unsigned short* w3l = (unsigned short*)p; p += (size_t)HID * HID * 2;
    unsigned short* w4h = (unsigned short*)p; p += (size_t)HID * OUT_DIM * 2;
    unsigned short* w4l = (unsigned short*)p; p += (size_t)HID * OUT_DIM * 2;

    hipMemsetAsync(counts, 0, (size_t)N * sizeof(int), stream);

    const int eb = (E + 255) / 256;
    const int nb = (N + 1023) / 1024;
    k_hist<<<eb, 256, 0, stream>>>(dst, E, counts);
    k_scan1<<<nb, 1024, 0, stream>>>(counts, N, offs, bsums);
    k_scan2<<<1, 256, 0, stream>>>(bsums, nb);
    k_scan3<<<nb, 1024, 0, stream>>>(offs, bsums, N, E, cursor);
    k_dinv<<<(N + 255) / 256, 256, 0, stream>>>(counts, N, dinv);
    k_fill<<<eb, 256, 0, stream>>>(src, dst, E, cursor, ssrc);

    k_splitW<<<(IN_DIM * HID + 255) / 256, 256, 0, stream>>>(W1, IN_DIM, HID, w1h, w1l);
    k_splitW<<<(HID * HID + 255) / 256, 256, 0, stream>>>(W2, HID, HID, w2h, w2l);
    k_splitW<<<(HID * HID + 255) / 256, 256, 0, stream>>>(W3, HID, HID, w3h, w3l);
    k_splitW<<<(HID * OUT_DIM + 255) / 256, 256, 0, stream>>>(W4, HID, OUT_DIM, w4h, w4l);

    const int gb = (N + 127) / 128;
    const int ab = (N + 3) / 4;
    k_gemm_mfma<IN_DIM, HID, true><<<gb, 256, 0, stream>>>(x, w1h, w1l, dinv, hbf, N);
    k_aggbf<<<ab, 256, 0, stream>>>((const unsigned*)hbf, offs, ssrc, dinv, b1, afp, N);
    k_gemm_mfma<HID, HID, true><<<gb, 256, 0, stream>>>(afp, w2h, w2l, dinv, hbf, N);
    k_aggbf<<<ab, 256, 0, stream>>>((const unsigned*)hbf, offs, ssrc, dinv, b2, afp, N);
    k_gemm_mfma<HID, HID, true><<<gb, 256, 0, stream>>>(afp, w3h, w3l, dinv, hbf, N);
    k_aggbf<<<ab, 256, 0, stream>>>((const unsigned*)hbf, offs, ssrc, dinv, b3, afp, N);
    k_gemm_mfma<HID, OUT_DIM, false><<<gb, 256, 0, stream>>>(afp, w4h, w4l, dinv, h4, N);
    k_agg64f<<<ab, 256, 0, stream>>>(h4, offs, ssrc, dinv, b4, (float*)d_out, N);
}